// Round 1
// baseline (239.966 us; speedup 1.0000x reference)
//
#include <hip/hip_runtime.h>
#include <hip/hip_bf16.h>

// E3TAOBackflow on MI355X — MFMA bf16, register-resident norms/gating.
// Reduction (verified R2/R3): antisymmetrization => scalar out = 0 exactly,
// vector out = (v @ [Wh0@Wu0]) * sigmoid([s,||v@Wh0||] @ Wm0 + bm0) @ C,
// C = Wh1@Wu1@W1/sqrt(S).  Wm1, bm1, W0 dead.  Output f32.
// t-split M: 3 GEMMs 16x128x256 sharing B-frags; cross-t norm and sigmoid
// gating stay in registers (D-layouts align); phase3 D stores directly to
// global as 3 floats (out col = nt*64 + 16 + 3*l15 + t). 3 barriers total.
// R4: v1 aliases xv (dead after phase1; B2 separates reads/writes) ->
// LDS 21504B; launch_bounds(256,5) -> 5 blocks/CU; zero-stores moved
// after B1 (drain under phase1 MFMA, not tail burst); nontemporal
// loads on x, nontemporal stores on out (touch-once streams).

typedef __attribute__((ext_vector_type(8))) short short8;
typedef __attribute__((ext_vector_type(4))) float floatx4;

static __device__ __forceinline__ unsigned short f2bf(float f) {
  unsigned u = __float_as_uint(f);
  u = (u + 0x7fffu + ((u >> 16) & 1u)) >> 16;  // RNE
  return (unsigned short)u;
}
static __device__ __forceinline__ unsigned pk2(float lo, float hi) {
  __hip_bfloat162 h = __float22bfloat162_rn(make_float2(lo, hi));
  return *(unsigned*)&h;  // low 16 = lo
}

// write element B[k][n] into swizzled fragment layout (KT = K/32)
static __device__ __forceinline__ void put_sw(unsigned short* B, int k, int n,
                                              float val, int KT) {
  int kt = k >> 5, quad = (k >> 3) & 3, j = k & 7;
  int nt = n >> 4, c = n & 15;
  int lane = quad * 16 + c;
  B[(((nt * KT + kt) * 64 + lane) << 3) + j] = f2bf(val);
}

// ---- prep1: Wcat = [Wh0 | Wh0@Wu0] -> Wcat_sw (128x256, KT=4); T = Wh1@Wu1
__global__ __launch_bounds__(128) void prep1(
    const float* __restrict__ Wh0, const float* __restrict__ Wu0,
    const float* __restrict__ Wh1, const float* __restrict__ Wu1,
    unsigned short* __restrict__ Wcat_sw, float* __restrict__ T) {
  int b = blockIdx.x, o = threadIdx.x;
  if (b < 128) {
    int m = b;
    float acc = 0.f;
    for (int h = 0; h < 128; ++h) acc += Wh0[m * 128 + h] * Wu0[h * 128 + o];
    put_sw(Wcat_sw, m, o, Wh0[m * 128 + o], 4);
    put_sw(Wcat_sw, m, o + 128, acc, 4);
  } else {
    int m = b - 128;
    float acc = 0.f;
    for (int h = 0; h < 128; ++h) acc += Wh1[m * 128 + h] * Wu1[h * 128 + o];
    T[m * 128 + o] = acc;
  }
}

// ---- prep2: C_sw = (T@W1)/sqrt(S) (128x256, KT=4); Wm0_sw (256x128, KT=8)
__global__ __launch_bounds__(256) void prep2(
    const float* __restrict__ T, const float* __restrict__ W1,
    const float* __restrict__ Wm0, unsigned short* __restrict__ C_sw,
    unsigned short* __restrict__ Wm0_sw) {
  int b = blockIdx.x, tid = threadIdx.x;
  if (b < 128) {
    int m = b, n = tid;
    float acc = 0.f;
    for (int h = 0; h < 128; ++h) acc += T[m * 128 + h] * W1[h * 256 + n];
    put_sw(C_sw, m, n, acc * 0.08838834764831845f, 4);
  } else {
    int k = (b - 128) * 2 + (tid >> 7);
    int n = tid & 127;
    put_sw(Wm0_sw, k, n, Wm0[k * 128 + n], 8);
  }
}

#define XA_S 264  // bf16 row stride for xa (256 + 8 pad; 528B = 33*16 ok)
#define XV_S 136  // bf16 row stride for xv/v1 (128 + 8 pad; 272B = 17*16 ok)
#define XV_T 2176 // elements per t-plane (16 * 136)

__global__ __launch_bounds__(256, 5) void main_k(
    const float* __restrict__ x, const float* __restrict__ bm0,
    const unsigned short* __restrict__ Wcat_sw,
    const unsigned short* __restrict__ Wm0_sw,
    const unsigned short* __restrict__ C_sw, float* __restrict__ out) {
  // LDS (21504 B): xv/v1 [0,13056) | xa [13056,21504)
  // v1 aliases xv: all xv reads are phase1 (pre-B2), all v1 writes post-B2.
  __shared__ __align__(16) unsigned char smem[21504];
  unsigned short* xv = (unsigned short*)smem;
  unsigned short* v1 = (unsigned short*)smem;
  unsigned short* xa = (unsigned short*)(smem + 13056);

  const int tid = threadIdx.x;
  const int lane = tid & 63;
  const int w = tid >> 6;
  const int l15 = lane & 15;
  const int quad = lane >> 4;
  const int r0 = blockIdx.x << 4;  // 16 rows/block
  const float* xrow = x + (size_t)r0 * 512;
  float* orow = out + (size_t)r0 * 1024;
  const int ntg[4] = {2 * w, 2 * w + 1, 8 + 2 * w, 9 + 2 * w};

  // bias for gate cols this lane will own (needed post-gate; load early)
  float bias0 = bm0[(2 * w) * 16 + l15];
  float bias1 = bm0[(2 * w + 1) * 16 + l15];

  // ---- stage: s -> xa bf16; v -> xv[t][r][m] bf16 (packed b64 writes)
#pragma unroll
  for (int i = 0; i < 2; ++i) {  // s: 512 float4 chunks
    int e = tid + 256 * i;
    int r = e >> 5, c0 = (e & 31) << 2;
    floatx4 s4 = __builtin_nontemporal_load(
        (const floatx4*)(xrow + r * 512 + c0));
    uint2 p = make_uint2(pk2(s4.x, s4.y), pk2(s4.z, s4.w));
    *(uint2*)(xa + r * XA_S + c0) = p;
  }
#pragma unroll
  for (int i = 0; i < 2; ++i) {  // v: 512 chunks of 12 floats (4 m x 3 t)
    int e = tid + 256 * i;
    int r = e >> 5, mc = e & 31;
    const float* p = xrow + r * 512 + 128 + mc * 12;
    floatx4 a = __builtin_nontemporal_load((const floatx4*)(p));
    floatx4 b = __builtin_nontemporal_load((const floatx4*)(p + 4));
    floatx4 c = __builtin_nontemporal_load((const floatx4*)(p + 8));
    float f[12] = {a.x, a.y, a.z, a.w, b.x, b.y, b.z, b.w, c.x, c.y, c.z, c.w};
#pragma unroll
    for (int t = 0; t < 3; ++t) {
      uint2 pk = make_uint2(pk2(f[t], f[t + 3]), pk2(f[t + 6], f[t + 9]));
      *(uint2*)(xv + t * XV_T + r * XV_S + mc * 4) = pk;
    }
  }
  __syncthreads();  // B1

  // ---- zero-stores for out (independent of everything): issue here so
  // they drain under phase1 MFMA instead of joining the tail store burst.
  const floatx4 zf4 = {0.f, 0.f, 0.f, 0.f};
#pragma unroll
  for (int i = 0; i < 4; ++i) {  // zeros: 1024 float4
    int e = tid + 256 * i;
    int r = e >> 6, gblk = (e >> 2) & 15, s4i = e & 3;
    __builtin_nontemporal_store(
        zf4, (floatx4*)(orow + (size_t)r * 1024 + gblk * 64 + s4i * 4));
  }

  // ---- phase1: per t, [Vh|Vu](16x256) = xv_t(16x128) @ Wcat; B shared over t
  floatx4 acc[3][4];
#pragma unroll
  for (int t = 0; t < 3; ++t)
#pragma unroll
    for (int j = 0; j < 4; ++j) acc[t][j] = zf4;
  for (int kt = 0; kt < 4; ++kt) {
    short8 bf[4];
#pragma unroll
    for (int j = 0; j < 4; ++j)
      bf[j] = *(const short8*)(Wcat_sw + (((ntg[j] * 4 + kt) * 64 + lane) << 3));
#pragma unroll
    for (int t = 0; t < 3; ++t) {
      short8 af = *(const short8*)(xv + t * XV_T + l15 * XV_S + kt * 32 + quad * 8);
#pragma unroll
      for (int j = 0; j < 4; ++j)
        acc[t][j] = __builtin_amdgcn_mfma_f32_16x16x32_bf16(af, bf[j], acc[t][j], 0, 0, 0);
    }
  }

  // ---- norms in registers: vn = sqrt(sum_t Vh_t^2 + eps) -> xa[:,128:]
#pragma unroll
  for (int j = 0; j < 2; ++j)
#pragma unroll
    for (int rg = 0; rg < 4; ++rg) {
      float s0 = acc[0][j][rg], s1 = acc[1][j][rg], s2 = acc[2][j][rg];
      float vn = sqrtf(s0 * s0 + s1 * s1 + s2 * s2 + 1e-8f);
      int r = quad * 4 + rg;
      int h = ntg[j] * 16 + l15;
      xa[r * XA_S + 128 + h] = f2bf(vn);
    }
  __syncthreads();  // B2

  // ---- gate GEMM: sm(16x128) = [s|vn](16x256) @ Wm0; wave w -> cols 2w,2w+1
  floatx4 ga[2] = {zf4, zf4};
  for (int kt = 0; kt < 8; ++kt) {
    short8 af = *(const short8*)(xa + l15 * XA_S + kt * 32 + quad * 8);
    short8 b0 = *(const short8*)(Wm0_sw + ((((2 * w) * 8 + kt) * 64 + lane) << 3));
    short8 b1 = *(const short8*)(Wm0_sw + ((((2 * w + 1) * 8 + kt) * 64 + lane) << 3));
    ga[0] = __builtin_amdgcn_mfma_f32_16x16x32_bf16(af, b0, ga[0], 0, 0, 0);
    ga[1] = __builtin_amdgcn_mfma_f32_16x16x32_bf16(af, b1, ga[1], 0, 0, 0);
  }
  // sigmoid + gating in registers: gate D-layout == Vu acc layout (lane-exact)
  float g[2][4];
#pragma unroll
  for (int j = 0; j < 2; ++j) {
    float bias = j ? bias1 : bias0;
#pragma unroll
    for (int rg = 0; rg < 4; ++rg)
      g[j][rg] = 1.f / (1.f + __expf(-(ga[j][rg] + bias)));
  }
#pragma unroll
  for (int t = 0; t < 3; ++t)
#pragma unroll
    for (int j = 0; j < 2; ++j)
#pragma unroll
      for (int rg = 0; rg < 4; ++rg) {
        int r = quad * 4 + rg;
        int o = (2 * w + j) * 16 + l15;  // Vu col within [0,128)
        v1[t * XV_T + r * XV_S + o] = f2bf(acc[t][2 + j][rg] * g[j][rg]);
      }
  __syncthreads();  // B3

  // ---- phase3: per t, vo_t(16x256) = v1_t(16x128) @ C; B shared over t
  floatx4 vacc[3][4];
#pragma unroll
  for (int t = 0; t < 3; ++t)
#pragma unroll
    for (int j = 0; j < 4; ++j) vacc[t][j] = zf4;
  for (int kt = 0; kt < 4; ++kt) {
    short8 bf[4];
#pragma unroll
    for (int j = 0; j < 4; ++j)
      bf[j] = *(const short8*)(C_sw + (((ntg[j] * 4 + kt) * 64 + lane) << 3));
#pragma unroll
    for (int t = 0; t < 3; ++t) {
      short8 af = *(const short8*)(v1 + t * XV_T + l15 * XV_S + kt * 32 + quad * 8);
#pragma unroll
      for (int j = 0; j < 4; ++j)
        vacc[t][j] = __builtin_amdgcn_mfma_f32_16x16x32_bf16(af, bf[j], vacc[t][j], 0, 0, 0);
    }
  }

  // ---- epilogue: direct nontemporal stores. Row layout: 16 groups of 64 =
  // [16 zeros | 48 data], data col = g*64 + 16 + 3*(n&15) + t with g = nt.
  // (zeros were already written after B1)
#pragma unroll
  for (int j = 0; j < 4; ++j) {
    int nt = ntg[j];
#pragma unroll
    for (int rg = 0; rg < 4; ++rg) {
      int r = quad * 4 + rg;
      float* dp = orow + (size_t)r * 1024 + nt * 64 + 16 + 3 * l15;
      __builtin_nontemporal_store(vacc[0][j][rg], dp);
      __builtin_nontemporal_store(vacc[1][j][rg], dp + 1);
      __builtin_nontemporal_store(vacc[2][j][rg], dp + 2);
    }
  }
}

extern "C" void kernel_launch(void* const* d_in, const int* in_sizes, int n_in,
                              void* d_out, int out_size, void* d_ws,
                              size_t ws_size, hipStream_t stream) {
  const float* mo = (const float*)d_in[0];
  const float* Wh0 = (const float*)d_in[1];
  const float* Wu0 = (const float*)d_in[2];
  const float* Wm0 = (const float*)d_in[3];
  const float* bm0 = (const float*)d_in[4];
  const float* Wh1 = (const float*)d_in[5];
  const float* Wu1 = (const float*)d_in[6];
  const float* W1 = (const float*)d_in[10];
  // d_in[7]=Wm1, d_in[8]=bm1, d_in[9]=W0: dead under antisymmetrization

  unsigned short* ws = (unsigned short*)d_ws;
  unsigned short* Wcat_sw = ws;         // 64 KB
  unsigned short* C_sw = ws + 32768;    // 64 KB
  unsigned short* Wm0_sw = ws + 65536;  // 64 KB
  float* T = (float*)(ws + 98304);      // 64 KB

  prep1<<<256, 128, 0, stream>>>(Wh0, Wu0, Wh1, Wu1, Wcat_sw, T);
  prep2<<<256, 256, 0, stream>>>(T, W1, Wm0, C_sw, Wm0_sw);

  main_k<<<2048, 256, 0, stream>>>(mo, bm0, Wcat_sw, Wm0_sw, C_sw,
                                   (float*)d_out);
}

// Round 3
// 235.463 us; speedup vs baseline: 1.0191x; 1.0191x over previous
//
#include <hip/hip_runtime.h>
#include <hip/hip_bf16.h>

// E3TAOBackflow on MI355X — MFMA bf16, register-resident norms/gating.
// Reduction (verified R2/R3): antisymmetrization => scalar out = 0 exactly,
// vector out = (v @ [Wh0@Wu0]) * sigmoid([s,||v@Wh0||] @ Wm0 + bm0) @ C,
// C = Wh1@Wu1@W1/sqrt(S).  Wm1, bm1, W0 dead.  Output f32.
// t-split M: 3 GEMMs 16x128x256 sharing B-frags; cross-t norm and sigmoid
// gating stay in registers (D-layouts align); phase3 D stores directly to
// global as 3 floats (out col = nt*64 + 16 + 3*l15 + t). 3 barriers total.
// R5: revert ALL nontemporal (4B nt stores caused partial-line HBM write
// amplification, R4 post-mortem). Keep LDS alias (v1=xv, 21504B) + zeros
// after B1. NEW: phase1 split into Vh pass then Vu pass, phase3 split into
// two halves with interleaved stores -> acc live set halves (~32 VGPR),
// so __launch_bounds__(256,5) fits spill-free -> 5 blocks/CU.
// R6: identical resubmit — R5 bench failed on infra (container), no data.

typedef __attribute__((ext_vector_type(8))) short short8;
typedef __attribute__((ext_vector_type(4))) float floatx4;

static __device__ __forceinline__ unsigned short f2bf(float f) {
  unsigned u = __float_as_uint(f);
  u = (u + 0x7fffu + ((u >> 16) & 1u)) >> 16;  // RNE
  return (unsigned short)u;
}
static __device__ __forceinline__ unsigned pk2(float lo, float hi) {
  __hip_bfloat162 h = __float22bfloat162_rn(make_float2(lo, hi));
  return *(unsigned*)&h;  // low 16 = lo
}

// write element B[k][n] into swizzled fragment layout (KT = K/32)
static __device__ __forceinline__ void put_sw(unsigned short* B, int k, int n,
                                              float val, int KT) {
  int kt = k >> 5, quad = (k >> 3) & 3, j = k & 7;
  int nt = n >> 4, c = n & 15;
  int lane = quad * 16 + c;
  B[(((nt * KT + kt) * 64 + lane) << 3) + j] = f2bf(val);
}

// ---- prep1: Wcat = [Wh0 | Wh0@Wu0] -> Wcat_sw (128x256, KT=4); T = Wh1@Wu1
__global__ __launch_bounds__(128) void prep1(
    const float* __restrict__ Wh0, const float* __restrict__ Wu0,
    const float* __restrict__ Wh1, const float* __restrict__ Wu1,
    unsigned short* __restrict__ Wcat_sw, float* __restrict__ T) {
  int b = blockIdx.x, o = threadIdx.x;
  if (b < 128) {
    int m = b;
    float acc = 0.f;
    for (int h = 0; h < 128; ++h) acc += Wh0[m * 128 + h] * Wu0[h * 128 + o];
    put_sw(Wcat_sw, m, o, Wh0[m * 128 + o], 4);
    put_sw(Wcat_sw, m, o + 128, acc, 4);
  } else {
    int m = b - 128;
    float acc = 0.f;
    for (int h = 0; h < 128; ++h) acc += Wh1[m * 128 + h] * Wu1[h * 128 + o];
    T[m * 128 + o] = acc;
  }
}

// ---- prep2: C_sw = (T@W1)/sqrt(S) (128x256, KT=4); Wm0_sw (256x128, KT=8)
__global__ __launch_bounds__(256) void prep2(
    const float* __restrict__ T, const float* __restrict__ W1,
    const float* __restrict__ Wm0, unsigned short* __restrict__ C_sw,
    unsigned short* __restrict__ Wm0_sw) {
  int b = blockIdx.x, tid = threadIdx.x;
  if (b < 128) {
    int m = b, n = tid;
    float acc = 0.f;
    for (int h = 0; h < 128; ++h) acc += T[m * 128 + h] * W1[h * 256 + n];
    put_sw(C_sw, m, n, acc * 0.08838834764831845f, 4);
  } else {
    int k = (b - 128) * 2 + (tid >> 7);
    int n = tid & 127;
    put_sw(Wm0_sw, k, n, Wm0[k * 128 + n], 8);
  }
}

#define XA_S 264  // bf16 row stride for xa (256 + 8 pad; 528B = 33*16 ok)
#define XV_S 136  // bf16 row stride for xv/v1 (128 + 8 pad; 272B = 17*16 ok)
#define XV_T 2176 // elements per t-plane (16 * 136)

__global__ __launch_bounds__(256, 5) void main_k(
    const float* __restrict__ x, const float* __restrict__ bm0,
    const unsigned short* __restrict__ Wcat_sw,
    const unsigned short* __restrict__ Wm0_sw,
    const unsigned short* __restrict__ C_sw, float* __restrict__ out) {
  // LDS (21504 B): xv/v1 [0,13056) | xa [13056,21504)
  // v1 aliases xv: all xv reads are pre-B2, all v1 writes post-B2.
  __shared__ __align__(16) unsigned char smem[21504];
  unsigned short* xv = (unsigned short*)smem;
  unsigned short* v1 = (unsigned short*)smem;
  unsigned short* xa = (unsigned short*)(smem + 13056);

  const int tid = threadIdx.x;
  const int lane = tid & 63;
  const int w = tid >> 6;
  const int l15 = lane & 15;
  const int quad = lane >> 4;
  const int r0 = blockIdx.x << 4;  // 16 rows/block
  const float* xrow = x + (size_t)r0 * 512;
  float* orow = out + (size_t)r0 * 1024;
  const int ntg[4] = {2 * w, 2 * w + 1, 8 + 2 * w, 9 + 2 * w};

  // bias for gate cols this lane will own (needed post-gate; load early)
  float bias0 = bm0[(2 * w) * 16 + l15];
  float bias1 = bm0[(2 * w + 1) * 16 + l15];

  // ---- stage: s -> xa bf16; v -> xv[t][r][m] bf16 (packed b64 writes)
#pragma unroll
  for (int i = 0; i < 2; ++i) {  // s: 512 float4 chunks
    int e = tid + 256 * i;
    int r = e >> 5, c0 = (e & 31) << 2;
    float4 s4 = *(const float4*)(xrow + r * 512 + c0);
    uint2 p = make_uint2(pk2(s4.x, s4.y), pk2(s4.z, s4.w));
    *(uint2*)(xa + r * XA_S + c0) = p;
  }
#pragma unroll
  for (int i = 0; i < 2; ++i) {  // v: 512 chunks of 12 floats (4 m x 3 t)
    int e = tid + 256 * i;
    int r = e >> 5, mc = e & 31;
    const float* p = xrow + r * 512 + 128 + mc * 12;
    float4 a = *(const float4*)(p);
    float4 b = *(const float4*)(p + 4);
    float4 c = *(const float4*)(p + 8);
    float f[12] = {a.x, a.y, a.z, a.w, b.x, b.y, b.z, b.w, c.x, c.y, c.z, c.w};
#pragma unroll
    for (int t = 0; t < 3; ++t) {
      uint2 pk = make_uint2(pk2(f[t], f[t + 3]), pk2(f[t + 6], f[t + 9]));
      *(uint2*)(xv + t * XV_T + r * XV_S + mc * 4) = pk;
    }
  }
  __syncthreads();  // B1

  // ---- zero-stores for out (independent of everything): issue here so
  // they drain under phase1 MFMA instead of joining the tail store burst.
  // Cached (NOT nontemporal): they merge with the later data stores in L2.
  const floatx4 zf4 = {0.f, 0.f, 0.f, 0.f};
#pragma unroll
  for (int i = 0; i < 4; ++i) {  // zeros: 1024 float4
    int e = tid + 256 * i;
    int r = e >> 6, gblk = (e >> 2) & 15, s4i = e & 3;
    *(floatx4*)(orow + (size_t)r * 1024 + gblk * 64 + s4i * 4) = zf4;
  }

  // ---- phase1a: per t, Vh(16x32) = xv_t(16x128) @ Wcat[:, ntg01]
  floatx4 accH[3][2];
#pragma unroll
  for (int t = 0; t < 3; ++t)
#pragma unroll
    for (int j = 0; j < 2; ++j) accH[t][j] = zf4;
  for (int kt = 0; kt < 4; ++kt) {
    short8 bf[2];
#pragma unroll
    for (int j = 0; j < 2; ++j)
      bf[j] = *(const short8*)(Wcat_sw + (((ntg[j] * 4 + kt) * 64 + lane) << 3));
#pragma unroll
    for (int t = 0; t < 3; ++t) {
      short8 af = *(const short8*)(xv + t * XV_T + l15 * XV_S + kt * 32 + quad * 8);
#pragma unroll
      for (int j = 0; j < 2; ++j)
        accH[t][j] = __builtin_amdgcn_mfma_f32_16x16x32_bf16(af, bf[j], accH[t][j], 0, 0, 0);
    }
  }

  // ---- norms in registers: vn = sqrt(sum_t Vh_t^2 + eps) -> xa[:,128:]
#pragma unroll
  for (int j = 0; j < 2; ++j)
#pragma unroll
    for (int rg = 0; rg < 4; ++rg) {
      float s0 = accH[0][j][rg], s1 = accH[1][j][rg], s2 = accH[2][j][rg];
      float vn = sqrtf(s0 * s0 + s1 * s1 + s2 * s2 + 1e-8f);
      int r = quad * 4 + rg;
      int h = ntg[j] * 16 + l15;
      xa[r * XA_S + 128 + h] = f2bf(vn);
    }

  // ---- phase1b: per t, Vu(16x32) = xv_t(16x128) @ Wcat[:, ntg23]
  // (accH dead now -> register pressure stays ~32 acc VGPRs)
  floatx4 accU[3][2];
#pragma unroll
  for (int t = 0; t < 3; ++t)
#pragma unroll
    for (int j = 0; j < 2; ++j) accU[t][j] = zf4;
  for (int kt = 0; kt < 4; ++kt) {
    short8 bf[2];
#pragma unroll
    for (int j = 0; j < 2; ++j)
      bf[j] = *(const short8*)(Wcat_sw + (((ntg[2 + j] * 4 + kt) * 64 + lane) << 3));
#pragma unroll
    for (int t = 0; t < 3; ++t) {
      short8 af = *(const short8*)(xv + t * XV_T + l15 * XV_S + kt * 32 + quad * 8);
#pragma unroll
      for (int j = 0; j < 2; ++j)
        accU[t][j] = __builtin_amdgcn_mfma_f32_16x16x32_bf16(af, bf[j], accU[t][j], 0, 0, 0);
    }
  }
  __syncthreads();  // B2

  // ---- gate GEMM: sm(16x128) = [s|vn](16x256) @ Wm0; wave w -> cols 2w,2w+1
  floatx4 ga[2] = {zf4, zf4};
  for (int kt = 0; kt < 8; ++kt) {
    short8 af = *(const short8*)(xa + l15 * XA_S + kt * 32 + quad * 8);
    short8 b0 = *(const short8*)(Wm0_sw + ((((2 * w) * 8 + kt) * 64 + lane) << 3));
    short8 b1 = *(const short8*)(Wm0_sw + ((((2 * w + 1) * 8 + kt) * 64 + lane) << 3));
    ga[0] = __builtin_amdgcn_mfma_f32_16x16x32_bf16(af, b0, ga[0], 0, 0, 0);
    ga[1] = __builtin_amdgcn_mfma_f32_16x16x32_bf16(af, b1, ga[1], 0, 0, 0);
  }
  // sigmoid + gating in registers: gate D-layout == Vu acc layout (lane-exact)
  float g[2][4];
#pragma unroll
  for (int j = 0; j < 2; ++j) {
    float bias = j ? bias1 : bias0;
#pragma unroll
    for (int rg = 0; rg < 4; ++rg)
      g[j][rg] = 1.f / (1.f + __expf(-(ga[j][rg] + bias)));
  }
#pragma unroll
  for (int t = 0; t < 3; ++t)
#pragma unroll
    for (int j = 0; j < 2; ++j)
#pragma unroll
      for (int rg = 0; rg < 4; ++rg) {
        int r = quad * 4 + rg;
        int o = (2 * w + j) * 16 + l15;  // Vu col within [0,128)
        v1[t * XV_T + r * XV_S + o] = f2bf(accU[t][j][rg] * g[j][rg]);
      }
  __syncthreads();  // B3

  // ---- phase3: per t, vo_t(16x256) = v1_t(16x128) @ C; two halves, each
  // half's stores issue before the next half's MFMA (spreads store burst,
  // halves vacc live set).
#pragma unroll
  for (int half = 0; half < 2; ++half) {
    floatx4 vacc[3][2];
#pragma unroll
    for (int t = 0; t < 3; ++t)
#pragma unroll
      for (int j = 0; j < 2; ++j) vacc[t][j] = zf4;
    for (int kt = 0; kt < 4; ++kt) {
      short8 bf[2];
#pragma unroll
      for (int j = 0; j < 2; ++j)
        bf[j] = *(const short8*)(C_sw +
                                 (((ntg[2 * half + j] * 4 + kt) * 64 + lane) << 3));
#pragma unroll
      for (int t = 0; t < 3; ++t) {
        short8 af = *(const short8*)(v1 + t * XV_T + l15 * XV_S + kt * 32 + quad * 8);
#pragma unroll
        for (int j = 0; j < 2; ++j)
          vacc[t][j] = __builtin_amdgcn_mfma_f32_16x16x32_bf16(af, bf[j], vacc[t][j], 0, 0, 0);
      }
    }
    // stores for this half. Row layout: 16 groups of 64 = [16 zeros | 48
    // data], data col = g*64 + 16 + 3*(n&15) + t with g = nt.
#pragma unroll
    for (int j = 0; j < 2; ++j) {
      int nt = ntg[2 * half + j];
#pragma unroll
      for (int rg = 0; rg < 4; ++rg) {
        int r = quad * 4 + rg;
        *(float3*)(orow + (size_t)r * 1024 + nt * 64 + 16 + 3 * l15) =
            make_float3(vacc[0][j][rg], vacc[1][j][rg], vacc[2][j][rg]);
      }
    }
  }
}

extern "C" void kernel_launch(void* const* d_in, const int* in_sizes, int n_in,
                              void* d_out, int out_size, void* d_ws,
                              size_t ws_size, hipStream_t stream) {
  const float* mo = (const float*)d_in[0];
  const float* Wh0 = (const float*)d_in[1];
  const float* Wu0 = (const float*)d_in[2];
  const float* Wm0 = (const float*)d_in[3];
  const float* bm0 = (const float*)d_in[4];
  const float* Wh1 = (const float*)d_in[5];
  const float* Wu1 = (const float*)d_in[6];
  const float* W1 = (const float*)d_in[10];
  // d_in[7]=Wm1, d_in[8]=bm1, d_in[9]=W0: dead under antisymmetrization

  unsigned short* ws = (unsigned short*)d_ws;
  unsigned short* Wcat_sw = ws;         // 64 KB
  unsigned short* C_sw = ws + 32768;    // 64 KB
  unsigned short* Wm0_sw = ws + 65536;  // 64 KB
  float* T = (float*)(ws + 98304);      // 64 KB

  prep1<<<256, 128, 0, stream>>>(Wh0, Wu0, Wh1, Wu1, Wcat_sw, T);
  prep2<<<256, 256, 0, stream>>>(T, W1, Wm0, C_sw, Wm0_sw);

  main_k<<<2048, 256, 0, stream>>>(mo, bm0, Wcat_sw, Wm0_sw, C_sw,
                                   (float*)d_out);
}

// Round 4
// 231.743 us; speedup vs baseline: 1.0355x; 1.0160x over previous
//
#include <hip/hip_runtime.h>
#include <hip/hip_bf16.h>

// E3TAOBackflow on MI355X — MFMA bf16, register-resident norms/gating.
// Reduction (verified R2/R3): antisymmetrization => scalar out = 0 exactly,
// vector out = (v @ [Wh0@Wu0]) * sigmoid([s,||v@Wh0||] @ Wm0 + bm0) @ C,
// C = Wh1@Wu1@W1/sqrt(S).  Wm1, bm1, W0 dead.  Output f32.
// t-split M: 3 GEMMs 16x128x256 sharing B-frags; cross-t norm and sigmoid
// gating stay in registers; phase3 D stores directly to global as 3 floats
// (out col = nt*64 + 16 + 3*l15 + t). 3 barriers total.
// R5: no nontemporal (4B nt stores = partial-line write amplification).
// LDS alias (v1=xv, 21504B); phase1 split Vh/Vu passes; phase3 split in
// halves; __launch_bounds__(256,5).
// R7: zero-stores moved from post-B1 to post-B3. Post-B1 placement put
// 16KB of stores into B2's s_waitcnt vmcnt(0) barrier drain -> critical-
// path stall (R6 post-mortem, ~13us). Post-B3 has NO downstream barrier:
// zeros drain under phase3 MFMA, off the critical path.

typedef __attribute__((ext_vector_type(8))) short short8;
typedef __attribute__((ext_vector_type(4))) float floatx4;

static __device__ __forceinline__ unsigned short f2bf(float f) {
  unsigned u = __float_as_uint(f);
  u = (u + 0x7fffu + ((u >> 16) & 1u)) >> 16;  // RNE
  return (unsigned short)u;
}
static __device__ __forceinline__ unsigned pk2(float lo, float hi) {
  __hip_bfloat162 h = __float22bfloat162_rn(make_float2(lo, hi));
  return *(unsigned*)&h;  // low 16 = lo
}

// write element B[k][n] into swizzled fragment layout (KT = K/32)
static __device__ __forceinline__ void put_sw(unsigned short* B, int k, int n,
                                              float val, int KT) {
  int kt = k >> 5, quad = (k >> 3) & 3, j = k & 7;
  int nt = n >> 4, c = n & 15;
  int lane = quad * 16 + c;
  B[(((nt * KT + kt) * 64 + lane) << 3) + j] = f2bf(val);
}

// ---- prep1: Wcat = [Wh0 | Wh0@Wu0] -> Wcat_sw (128x256, KT=4); T = Wh1@Wu1
__global__ __launch_bounds__(128) void prep1(
    const float* __restrict__ Wh0, const float* __restrict__ Wu0,
    const float* __restrict__ Wh1, const float* __restrict__ Wu1,
    unsigned short* __restrict__ Wcat_sw, float* __restrict__ T) {
  int b = blockIdx.x, o = threadIdx.x;
  if (b < 128) {
    int m = b;
    float acc = 0.f;
    for (int h = 0; h < 128; ++h) acc += Wh0[m * 128 + h] * Wu0[h * 128 + o];
    put_sw(Wcat_sw, m, o, Wh0[m * 128 + o], 4);
    put_sw(Wcat_sw, m, o + 128, acc, 4);
  } else {
    int m = b - 128;
    float acc = 0.f;
    for (int h = 0; h < 128; ++h) acc += Wh1[m * 128 + h] * Wu1[h * 128 + o];
    T[m * 128 + o] = acc;
  }
}

// ---- prep2: C_sw = (T@W1)/sqrt(S) (128x256, KT=4); Wm0_sw (256x128, KT=8)
__global__ __launch_bounds__(256) void prep2(
    const float* __restrict__ T, const float* __restrict__ W1,
    const float* __restrict__ Wm0, unsigned short* __restrict__ C_sw,
    unsigned short* __restrict__ Wm0_sw) {
  int b = blockIdx.x, tid = threadIdx.x;
  if (b < 128) {
    int m = b, n = tid;
    float acc = 0.f;
    for (int h = 0; h < 128; ++h) acc += T[m * 128 + h] * W1[h * 256 + n];
    put_sw(C_sw, m, n, acc * 0.08838834764831845f, 4);
  } else {
    int k = (b - 128) * 2 + (tid >> 7);
    int n = tid & 127;
    put_sw(Wm0_sw, k, n, Wm0[k * 128 + n], 8);
  }
}

#define XA_S 264  // bf16 row stride for xa (256 + 8 pad; 528B = 33*16 ok)
#define XV_S 136  // bf16 row stride for xv/v1 (128 + 8 pad; 272B = 17*16 ok)
#define XV_T 2176 // elements per t-plane (16 * 136)

__global__ __launch_bounds__(256, 5) void main_k(
    const float* __restrict__ x, const float* __restrict__ bm0,
    const unsigned short* __restrict__ Wcat_sw,
    const unsigned short* __restrict__ Wm0_sw,
    const unsigned short* __restrict__ C_sw, float* __restrict__ out) {
  // LDS (21504 B): xv/v1 [0,13056) | xa [13056,21504)
  // v1 aliases xv: all xv reads are pre-B2, all v1 writes post-B2.
  __shared__ __align__(16) unsigned char smem[21504];
  unsigned short* xv = (unsigned short*)smem;
  unsigned short* v1 = (unsigned short*)smem;
  unsigned short* xa = (unsigned short*)(smem + 13056);

  const int tid = threadIdx.x;
  const int lane = tid & 63;
  const int w = tid >> 6;
  const int l15 = lane & 15;
  const int quad = lane >> 4;
  const int r0 = blockIdx.x << 4;  // 16 rows/block
  const float* xrow = x + (size_t)r0 * 512;
  float* orow = out + (size_t)r0 * 1024;
  const int ntg[4] = {2 * w, 2 * w + 1, 8 + 2 * w, 9 + 2 * w};

  // bias for gate cols this lane will own (needed post-gate; load early)
  float bias0 = bm0[(2 * w) * 16 + l15];
  float bias1 = bm0[(2 * w + 1) * 16 + l15];

  // ---- stage: s -> xa bf16; v -> xv[t][r][m] bf16 (packed b64 writes)
#pragma unroll
  for (int i = 0; i < 2; ++i) {  // s: 512 float4 chunks
    int e = tid + 256 * i;
    int r = e >> 5, c0 = (e & 31) << 2;
    float4 s4 = *(const float4*)(xrow + r * 512 + c0);
    uint2 p = make_uint2(pk2(s4.x, s4.y), pk2(s4.z, s4.w));
    *(uint2*)(xa + r * XA_S + c0) = p;
  }
#pragma unroll
  for (int i = 0; i < 2; ++i) {  // v: 512 chunks of 12 floats (4 m x 3 t)
    int e = tid + 256 * i;
    int r = e >> 5, mc = e & 31;
    const float* p = xrow + r * 512 + 128 + mc * 12;
    float4 a = *(const float4*)(p);
    float4 b = *(const float4*)(p + 4);
    float4 c = *(const float4*)(p + 8);
    float f[12] = {a.x, a.y, a.z, a.w, b.x, b.y, b.z, b.w, c.x, c.y, c.z, c.w};
#pragma unroll
    for (int t = 0; t < 3; ++t) {
      uint2 pk = make_uint2(pk2(f[t], f[t + 3]), pk2(f[t + 6], f[t + 9]));
      *(uint2*)(xv + t * XV_T + r * XV_S + mc * 4) = pk;
    }
  }
  __syncthreads();  // B1

  const floatx4 zf4 = {0.f, 0.f, 0.f, 0.f};

  // ---- phase1a: per t, Vh(16x32) = xv_t(16x128) @ Wcat[:, ntg01]
  floatx4 accH[3][2];
#pragma unroll
  for (int t = 0; t < 3; ++t)
#pragma unroll
    for (int j = 0; j < 2; ++j) accH[t][j] = zf4;
  for (int kt = 0; kt < 4; ++kt) {
    short8 bf[2];
#pragma unroll
    for (int j = 0; j < 2; ++j)
      bf[j] = *(const short8*)(Wcat_sw + (((ntg[j] * 4 + kt) * 64 + lane) << 3));
#pragma unroll
    for (int t = 0; t < 3; ++t) {
      short8 af = *(const short8*)(xv + t * XV_T + l15 * XV_S + kt * 32 + quad * 8);
#pragma unroll
      for (int j = 0; j < 2; ++j)
        accH[t][j] = __builtin_amdgcn_mfma_f32_16x16x32_bf16(af, bf[j], accH[t][j], 0, 0, 0);
    }
  }

  // ---- norms in registers: vn = sqrt(sum_t Vh_t^2 + eps) -> xa[:,128:]
#pragma unroll
  for (int j = 0; j < 2; ++j)
#pragma unroll
    for (int rg = 0; rg < 4; ++rg) {
      float s0 = accH[0][j][rg], s1 = accH[1][j][rg], s2 = accH[2][j][rg];
      float vn = sqrtf(s0 * s0 + s1 * s1 + s2 * s2 + 1e-8f);
      int r = quad * 4 + rg;
      int h = ntg[j] * 16 + l15;
      xa[r * XA_S + 128 + h] = f2bf(vn);
    }

  // ---- phase1b: per t, Vu(16x32) = xv_t(16x128) @ Wcat[:, ntg23]
  // (accH dead now -> register pressure stays ~32 acc VGPRs)
  floatx4 accU[3][2];
#pragma unroll
  for (int t = 0; t < 3; ++t)
#pragma unroll
    for (int j = 0; j < 2; ++j) accU[t][j] = zf4;
  for (int kt = 0; kt < 4; ++kt) {
    short8 bf[2];
#pragma unroll
    for (int j = 0; j < 2; ++j)
      bf[j] = *(const short8*)(Wcat_sw + (((ntg[2 + j] * 4 + kt) * 64 + lane) << 3));
#pragma unroll
    for (int t = 0; t < 3; ++t) {
      short8 af = *(const short8*)(xv + t * XV_T + l15 * XV_S + kt * 32 + quad * 8);
#pragma unroll
      for (int j = 0; j < 2; ++j)
        accU[t][j] = __builtin_amdgcn_mfma_f32_16x16x32_bf16(af, bf[j], accU[t][j], 0, 0, 0);
    }
  }
  __syncthreads();  // B2

  // ---- gate GEMM: sm(16x128) = [s|vn](16x256) @ Wm0; wave w -> cols 2w,2w+1
  floatx4 ga[2] = {zf4, zf4};
  for (int kt = 0; kt < 8; ++kt) {
    short8 af = *(const short8*)(xa + l15 * XA_S + kt * 32 + quad * 8);
    short8 b0 = *(const short8*)(Wm0_sw + ((((2 * w) * 8 + kt) * 64 + lane) << 3));
    short8 b1 = *(const short8*)(Wm0_sw + ((((2 * w + 1) * 8 + kt) * 64 + lane) << 3));
    ga[0] = __builtin_amdgcn_mfma_f32_16x16x32_bf16(af, b0, ga[0], 0, 0, 0);
    ga[1] = __builtin_amdgcn_mfma_f32_16x16x32_bf16(af, b1, ga[1], 0, 0, 0);
  }
  // sigmoid + gating in registers: gate D-layout == Vu acc layout (lane-exact)
  float g[2][4];
#pragma unroll
  for (int j = 0; j < 2; ++j) {
    float bias = j ? bias1 : bias0;
#pragma unroll
    for (int rg = 0; rg < 4; ++rg)
      g[j][rg] = 1.f / (1.f + __expf(-(ga[j][rg] + bias)));
  }
#pragma unroll
  for (int t = 0; t < 3; ++t)
#pragma unroll
    for (int j = 0; j < 2; ++j)
#pragma unroll
      for (int rg = 0; rg < 4; ++rg) {
        int r = quad * 4 + rg;
        int o = (2 * w + j) * 16 + l15;  // Vu col within [0,128)
        v1[t * XV_T + r * XV_S + o] = f2bf(accU[t][j][rg] * g[j][rg]);
      }
  __syncthreads();  // B3

  // ---- zero-stores for out: issued HERE (post-B3) — no downstream barrier,
  // so no forced vmcnt(0) drain; they trickle out under phase3 MFMA.
  // Zeros occupy their own 64B lines (cols 0..15 of each 64-float group),
  // so no L2 merge interaction with the data stores.
#pragma unroll
  for (int i = 0; i < 4; ++i) {  // zeros: 1024 float4
    int e = tid + 256 * i;
    int r = e >> 6, gblk = (e >> 2) & 15, s4i = e & 3;
    *(floatx4*)(orow + (size_t)r * 1024 + gblk * 64 + s4i * 4) = zf4;
  }

  // ---- phase3: per t, vo_t(16x256) = v1_t(16x128) @ C; two halves, each
  // half's stores issue before the next half's MFMA (spreads store burst,
  // halves vacc live set).
#pragma unroll
  for (int half = 0; half < 2; ++half) {
    floatx4 vacc[3][2];
#pragma unroll
    for (int t = 0; t < 3; ++t)
#pragma unroll
      for (int j = 0; j < 2; ++j) vacc[t][j] = zf4;
    for (int kt = 0; kt < 4; ++kt) {
      short8 bf[2];
#pragma unroll
      for (int j = 0; j < 2; ++j)
        bf[j] = *(const short8*)(C_sw +
                                 (((ntg[2 * half + j] * 4 + kt) * 64 + lane) << 3));
#pragma unroll
      for (int t = 0; t < 3; ++t) {
        short8 af = *(const short8*)(v1 + t * XV_T + l15 * XV_S + kt * 32 + quad * 8);
#pragma unroll
        for (int j = 0; j < 2; ++j)
          vacc[t][j] = __builtin_amdgcn_mfma_f32_16x16x32_bf16(af, bf[j], vacc[t][j], 0, 0, 0);
      }
    }
    // stores for this half. Row layout: 16 groups of 64 = [16 zeros | 48
    // data], data col = g*64 + 16 + 3*(n&15) + t with g = nt.
#pragma unroll
    for (int j = 0; j < 2; ++j) {
      int nt = ntg[2 * half + j];
#pragma unroll
      for (int rg = 0; rg < 4; ++rg) {
        int r = quad * 4 + rg;
        *(float3*)(orow + (size_t)r * 1024 + nt * 64 + 16 + 3 * l15) =
            make_float3(vacc[0][j][rg], vacc[1][j][rg], vacc[2][j][rg]);
      }
    }
  }
}

extern "C" void kernel_launch(void* const* d_in, const int* in_sizes, int n_in,
                              void* d_out, int out_size, void* d_ws,
                              size_t ws_size, hipStream_t stream) {
  const float* mo = (const float*)d_in[0];
  const float* Wh0 = (const float*)d_in[1];
  const float* Wu0 = (const float*)d_in[2];
  const float* Wm0 = (const float*)d_in[3];
  const float* bm0 = (const float*)d_in[4];
  const float* Wh1 = (const float*)d_in[5];
  const float* Wu1 = (const float*)d_in[6];
  const float* W1 = (const float*)d_in[10];
  // d_in[7]=Wm1, d_in[8]=bm1, d_in[9]=W0: dead under antisymmetrization

  unsigned short* ws = (unsigned short*)d_ws;
  unsigned short* Wcat_sw = ws;         // 64 KB
  unsigned short* C_sw = ws + 32768;    // 64 KB
  unsigned short* Wm0_sw = ws + 65536;  // 64 KB
  float* T = (float*)(ws + 98304);      // 64 KB

  prep1<<<256, 128, 0, stream>>>(Wh0, Wu0, Wh1, Wu1, Wcat_sw, T);
  prep2<<<256, 256, 0, stream>>>(T, W1, Wm0, C_sw, Wm0_sw);

  main_k<<<2048, 256, 0, stream>>>(mo, bm0, Wcat_sw, Wm0_sw, C_sw,
                                   (float*)d_out);
}